// Round 1
// baseline (480.344 us; speedup 1.0000x reference)
//
#include <hip/hip_runtime.h>

#define NNODES 20000
#define NEDGES 200000

// ---------------------------------------------------------------------------
// Zero-fill (float4 granularity). n4 = number of float4 elements.
// ---------------------------------------------------------------------------
__global__ __launch_bounds__(256)
void zero_kernel(float4* __restrict__ p, long n4)
{
    long i = (long)blockIdx.x * 256 + threadIdx.x;
    if (i < n4) p[i] = make_float4(0.f, 0.f, 0.f, 0.f);
}

// ---------------------------------------------------------------------------
// CSR build, both directions batched via blockIdx.y / blockIdx.x(scan):
// histogram -> single-block-per-direction scan -> scatter
// ---------------------------------------------------------------------------
__global__ __launch_bounds__(256)
void hist2_kernel(const int* __restrict__ dst0, const int* __restrict__ dst1,
                  int* __restrict__ deg0, int* __restrict__ deg1, int n)
{
    const int e = blockIdx.x * 256 + threadIdx.x;
    if (e >= n) return;
    if (blockIdx.y == 0) atomicAdd(&deg0[dst0[e]], 1);
    else                 atomicAdd(&deg1[dst1[e]], 1);
}

// exclusive scan of deg -> rowptr[0..n], copy into cursor. One 1024-thread
// block per direction (gridDim.x == 2).
__global__ __launch_bounds__(1024)
void scan2_kernel(const int* __restrict__ deg0, const int* __restrict__ deg1,
                  int* __restrict__ rp0, int* __restrict__ rp1,
                  int* __restrict__ cur0, int* __restrict__ cur1, int n)
{
    const int* deg = blockIdx.x == 0 ? deg0 : deg1;
    int* rowptr    = blockIdx.x == 0 ? rp0  : rp1;
    int* cursor    = blockIdx.x == 0 ? cur0 : cur1;

    __shared__ int part[1024];
    const int t  = threadIdx.x;
    const int CH = (n + 1023) / 1024;
    const int base = t * CH;

    int s = 0;
    for (int i = 0; i < CH; ++i) {
        int idx = base + i;
        if (idx < n) s += deg[idx];
    }
    part[t] = s;
    __syncthreads();
    for (int off = 1; off < 1024; off <<= 1) {
        int v = 0;
        if (t >= off) v = part[t - off];
        __syncthreads();
        if (t >= off) part[t] += v;
        __syncthreads();
    }
    int run = (t == 0) ? 0 : part[t - 1];
    for (int i = 0; i < CH; ++i) {
        int idx = base + i;
        if (idx < n) {
            int dv = deg[idx];
            rowptr[idx] = run;
            cursor[idx] = run;
            run += dv;
        }
    }
    if (t == 1023) rowptr[n] = part[1023];
}

__global__ __launch_bounds__(256)
void scatter2_kernel(const int* __restrict__ dst0, const int* __restrict__ dst1,
                     int* __restrict__ cur0, int* __restrict__ cur1,
                     int* __restrict__ ei0, int* __restrict__ ei1, int n)
{
    const int e = blockIdx.x * 256 + threadIdx.x;
    if (e >= n) return;
    if (blockIdx.y == 0) { int p = atomicAdd(&cur0[dst0[e]], 1); ei0[p] = e; }
    else                 { int p = atomicAdd(&cur1[dst1[e]], 1); ei1[p] = e; }
}

// ---------------------------------------------------------------------------
// Segmented attention-aggregation v3, both directions batched (blockIdx.y).
// One 128-thread block per dst node; thread c owns channel c.
// Max-subtraction cancels algebraically; |x| small -> no fp32 overflow.
// Writes agg = (sum hve*p)/(sum p) once per node — no fp32 atomics.
// ---------------------------------------------------------------------------
__global__ __launch_bounds__(128)
void agg3_kernel(const float* __restrict__ fn0, const float* __restrict__ fe0,
                 const float* __restrict__ ha0, const int* __restrict__ src0,
                 const int* __restrict__ ei0,  const int* __restrict__ rp0,
                 float* __restrict__ agg0,
                 const float* __restrict__ fn1, const float* __restrict__ fe1,
                 const float* __restrict__ ha1, const int* __restrict__ src1,
                 const int* __restrict__ ei1,  const int* __restrict__ rp1,
                 float* __restrict__ agg1)
{
    const int y = blockIdx.y;
    const float* __restrict__ feat_node = y == 0 ? fn0 : fn1;
    const float* __restrict__ feat_edge = y == 0 ? fe0 : fe1;
    const float* __restrict__ h_att     = y == 0 ? ha0 : ha1;
    const int*   __restrict__ src       = y == 0 ? src0 : src1;
    const int*   __restrict__ eidx      = y == 0 ? ei0 : ei1;
    const int*   __restrict__ rowptr    = y == 0 ? rp0 : rp1;
    float*       __restrict__ agg       = y == 0 ? agg0 : agg1;

    const int d = blockIdx.x;
    const int c = threadIdx.x;
    const int lo = rowptr[d], hi = rowptr[d + 1];
    const bool low = c < 64;

    __shared__ int se[64];
    __shared__ int ss[64];

    float ssum = 0.f, anum = 0.f;

    for (int base = lo; base < hi; base += 64) {
        const int cnt = min(64, hi - base);
        if (c < cnt) {
            const int e = eidx[base + c];   // coalesced: contiguous in CSR
            se[c] = e;
            ss[c] = src[e];                 // lane-parallel gather
        }
        __syncthreads();

        int i = 0;
        for (; i + 4 <= cnt; i += 4) {
            float hv[4], at[4];
            #pragma unroll
            for (int j = 0; j < 4; ++j) {
                const int e = se[i + j];    // LDS broadcast (same addr)
                const int s = ss[i + j];
                hv[j] = low ? feat_node[(long)s * 64 + c]
                            : feat_edge[(long)e * 64 + (c - 64)];
                at[j] = h_att[(long)s * 128 + c];
            }
            #pragma unroll
            for (int j = 0; j < 4; ++j) {
                const float p = __expf(hv[j] * at[j]);
                ssum += p;
                anum += hv[j] * p;
            }
        }
        for (; i < cnt; ++i) {
            const int e = se[i];
            const int s = ss[i];
            const float hvv = low ? feat_node[(long)s * 64 + c]
                                  : feat_edge[(long)e * 64 + (c - 64)];
            const float att = h_att[(long)s * 128 + c];
            const float p = __expf(hvv * att);
            ssum += p;
            anum += hvv * p;
        }
        __syncthreads();
    }
    agg[(long)d * 128 + c] = (hi > lo) ? anum / ssum : 0.f;
}

// ---------------------------------------------------------------------------
// Batched tiled linear: up to 5 independent (x, W, bias, out) problems of the
// same shape, selected by blockIdx.y. 4x4 per-thread micro-tile.
// Round-6: W is NOT staged in LDS anymore (it is 16-32 KB, read-only,
// wave-coalesced row reads -> L1-resident). Halves LDS per block -> 2x
// blocks/CU (occupancy was the round-5 limiter: 37%, VALU 44%, HBM 38%).
// xs padded to BR+4 so the 4 row-reads per k are ONE aligned ds_read_b128
// (16-lane broadcast, conflict-free).
// ---------------------------------------------------------------------------
struct LinArgs {
    const float* x[5];
    const float* W[5];
    const float* bias[5];
    float*       out[5];
    long         ostride[5];
};

template<int DIN, int DOUT, int BLOCK, bool RELU>
__global__ __launch_bounds__(BLOCK)
void lin_batch_kernel(LinArgs a, int nrows)
{
    constexpr int BR  = 16 * BLOCK / DOUT;
    constexpr int BRP = BR + 4;              // keep 16B alignment of rt*4
    constexpr int KV  = DIN / 4;
    constexpr int JT  = DOUT / 4;

    const int y = blockIdx.y;
    const float* __restrict__ x    = a.x[y];
    const float* __restrict__ W    = a.W[y];
    const float* __restrict__ bias = a.bias[y];
    float* __restrict__ out        = a.out[y];
    const long ostride             = a.ostride[y];

    __shared__ float xs[DIN * BRP];

    const int tid  = threadIdx.x;
    const int row0 = blockIdx.x * BR;

    const int kv = tid % KV;
    for (int rr = tid / KV; rr < BR; rr += BLOCK / KV) {
        const int row = row0 + rr;
        float4 v = make_float4(0.f, 0.f, 0.f, 0.f);
        if (row < nrows)
            v = ((const float4*)x)[(long)row * KV + kv];
        xs[(kv * 4 + 0) * BRP + rr] = v.x;
        xs[(kv * 4 + 1) * BRP + rr] = v.y;
        xs[(kv * 4 + 2) * BRP + rr] = v.z;
        xs[(kv * 4 + 3) * BRP + rr] = v.w;
    }
    __syncthreads();

    const int jt = tid % JT;
    const int rt = tid / JT;

    float4 b4 = ((const float4*)bias)[jt];
    float acc[4][4];
    #pragma unroll
    for (int r = 0; r < 4; ++r) {
        acc[r][0] = b4.x; acc[r][1] = b4.y; acc[r][2] = b4.z; acc[r][3] = b4.w;
    }

    const float4* __restrict__ W4 = (const float4*)W;
    #pragma unroll 4
    for (int k = 0; k < DIN; ++k) {
        float4 w  = W4[k * JT + jt];                         // L1-hit, coalesced
        float4 x4 = *((const float4*)(xs + k * BRP + rt * 4)); // ds_read_b128
        float xr[4] = {x4.x, x4.y, x4.z, x4.w};
        #pragma unroll
        for (int r = 0; r < 4; ++r) {
            acc[r][0] = fmaf(xr[r], w.x, acc[r][0]);
            acc[r][1] = fmaf(xr[r], w.y, acc[r][1]);
            acc[r][2] = fmaf(xr[r], w.z, acc[r][2]);
            acc[r][3] = fmaf(xr[r], w.w, acc[r][3]);
        }
    }

    #pragma unroll
    for (int r = 0; r < 4; ++r) {
        const int row = row0 + rt * 4 + r;
        if (row >= nrows) continue;
        float4 o = make_float4(acc[r][0], acc[r][1], acc[r][2], acc[r][3]);
        if (RELU) {
            o.x = fmaxf(o.x, 0.f); o.y = fmaxf(o.y, 0.f);
            o.z = fmaxf(o.z, 0.f); o.w = fmaxf(o.w, 0.f);
        }
        *((float4*)(out + (long)row * ostride) + jt) = o;
    }
}

// ---------------------------------------------------------------------------
// Batched edge linear (both directions, blockIdx.y):
//   out = relu(x @ w_e + b_e + tabA[idxA[r]] + tabB[idxB[r]])
// Same round-6 restructure: W from L1 (no LDS stage), xs pad +4, b128 reads.
// LDS 33280 -> 17408 B per block: 4 -> 8 blocks/CU (thread-capped).
// ---------------------------------------------------------------------------
struct EdgeArgs {
    const float* x[2];
    const float* tabA[2];
    const float* tabB[2];
    const int*   idxA[2];
    const int*   idxB[2];
    float*       out[2];
};

__global__ __launch_bounds__(256)
void edge_batch_kernel(EdgeArgs a, const float* __restrict__ W,
                       const float* __restrict__ bias, int nrows)
{
    constexpr int DIN = 64, DOUT = 64, BLOCK = 256;
    constexpr int BR  = 16 * BLOCK / DOUT;   // 64
    constexpr int BRP = BR + 4;              // 68: rt*4 stays 16B-aligned
    constexpr int KV  = DIN / 4;             // 16
    constexpr int JT  = DOUT / 4;            // 16

    const int y = blockIdx.y;
    const float* __restrict__ x    = a.x[y];
    const float* __restrict__ tabA = a.tabA[y];
    const float* __restrict__ tabB = a.tabB[y];
    const int* __restrict__ idxA   = a.idxA[y];
    const int* __restrict__ idxB   = a.idxB[y];
    float* __restrict__ out        = a.out[y];

    __shared__ float xs[DIN * BRP];

    const int tid  = threadIdx.x;
    const int row0 = blockIdx.x * BR;

    const int kv = tid % KV;
    for (int rr = tid / KV; rr < BR; rr += BLOCK / KV) {
        const int row = row0 + rr;
        float4 v = make_float4(0.f, 0.f, 0.f, 0.f);
        if (row < nrows)
            v = ((const float4*)x)[(long)row * KV + kv];
        xs[(kv * 4 + 0) * BRP + rr] = v.x;
        xs[(kv * 4 + 1) * BRP + rr] = v.y;
        xs[(kv * 4 + 2) * BRP + rr] = v.z;
        xs[(kv * 4 + 3) * BRP + rr] = v.w;
    }
    __syncthreads();

    const int jt = tid % JT;
    const int rt = tid / JT;

    float4 b4 = ((const float4*)bias)[jt];
    float acc[4][4];
    #pragma unroll
    for (int r = 0; r < 4; ++r) {
        acc[r][0] = b4.x; acc[r][1] = b4.y; acc[r][2] = b4.z; acc[r][3] = b4.w;
    }

    const float4* __restrict__ W4 = (const float4*)W;
    #pragma unroll 4
    for (int k = 0; k < DIN; ++k) {
        float4 w  = W4[k * JT + jt];                           // L1-hit
        float4 x4 = *((const float4*)(xs + k * BRP + rt * 4)); // ds_read_b128
        float xr[4] = {x4.x, x4.y, x4.z, x4.w};
        #pragma unroll
        for (int r = 0; r < 4; ++r) {
            acc[r][0] = fmaf(xr[r], w.x, acc[r][0]);
            acc[r][1] = fmaf(xr[r], w.y, acc[r][1]);
            acc[r][2] = fmaf(xr[r], w.z, acc[r][2]);
            acc[r][3] = fmaf(xr[r], w.w, acc[r][3]);
        }
    }

    #pragma unroll
    for (int r = 0; r < 4; ++r) {
        const int row = row0 + rt * 4 + r;
        if (row >= nrows) continue;
        const int ia = idxA[row];
        const int ib = idxB[row];
        float4 ga = ((const float4*)(tabA + (long)ia * DOUT))[jt];
        float4 gb = ((const float4*)(tabB + (long)ib * DOUT))[jt];
        float4 o;
        o.x = fmaxf(acc[r][0] + ga.x + gb.x, 0.f);
        o.y = fmaxf(acc[r][1] + ga.y + gb.y, 0.f);
        o.z = fmaxf(acc[r][2] + ga.z + gb.z, 0.f);
        o.w = fmaxf(acc[r][3] + ga.w + gb.w, 0.f);
        *((float4*)(out + (long)row * DOUT) + jt) = o;
    }
}

// ---------------------------------------------------------------------------
extern "C" void kernel_launch(void* const* d_in, const int* in_sizes, int n_in,
                              void* d_out, int out_size, void* d_ws, size_t ws_size,
                              hipStream_t stream)
{
    const float* f_feat = (const float*)d_in[0];
    const float* b_feat = (const float*)d_in[1];
    const float* u_feat = (const float*)d_in[2];
    const float* v_feat = (const float*)d_in[3];
    const int* fw_src = (const int*)d_in[4];
    const int* fw_dst = (const int*)d_in[5];
    const int* bw_src = (const int*)d_in[6];
    const int* bw_dst = (const int*)d_in[7];
    const float* w_e  = (const float*)d_in[8];   const float* b_e  = (const float*)d_in[9];
    const float* w_u  = (const float*)d_in[10];  const float* b_u  = (const float*)d_in[11];
    const float* w_v  = (const float*)d_in[12];  const float* b_v  = (const float*)d_in[13];
    const float* w_au = (const float*)d_in[14];  const float* b_au = (const float*)d_in[15];
    const float* w_av = (const float*)d_in[16];  const float* b_av = (const float*)d_in[17];
    const float* w_Wu = (const float*)d_in[18];  const float* b_Wu = (const float*)d_in[19];
    const float* w_Wv = (const float*)d_in[20];  const float* b_Wv = (const float*)d_in[21];
    const float* w_Vu = (const float*)d_in[22];  const float* b_Vu = (const float*)d_in[23];
    const float* w_Vv = (const float*)d_in[24];  const float* b_Vv = (const float*)d_in[25];

    const int N = NNODES, E = NEDGES;

    // outputs: (hf, hb, hu, hv) concatenated flat
    float* out = (float*)d_out;
    float* hf = out;                       // [E,64]  (written LAST)
    float* hb = hf + (long)E * 64;         // [E,64]  (written LAST)
    float* hu = hb + (long)E * 64;         // [N,128]
    float* hv = hu + (long)N * 128;        // [N,128]

    // h_att_u / h_att_v staged in the hf region of d_out (2*N*128 floats
    // < E*64). Consumed by agg, then hf overwritten by the edge batch LAST.
    float* h_att_u = hf;                   // [N,128]
    float* h_att_v = h_att_u + (long)N * 128;

    // workspace: floats 3*N*64 + 2*N*128 = 8.96M; ints 6N+2+2E = 0.52M
    float* ws = (float*)d_ws;
    float* src_he_u = ws;                        // [N,64] (== dst_he_u)
    float* src_he_v = src_he_u + (long)N * 64;   // [N,64]
    float* dst_he_v = src_he_v + (long)N * 64;   // [N,64]
    float* agg_u    = dst_he_v + (long)N * 64;   // [N,128]
    float* agg_v    = agg_u    + (long)N * 128;  // [N,128]
    int*   ibase    = (int*)(agg_v + (long)N * 128);
    int* deg_b    = ibase;                 // [N] zeroed
    int* deg_f    = deg_b + N;             // [N] zeroed
    int* rowptr_b = deg_f + N;             // [N+1]
    int* rowptr_f = rowptr_b + (N + 1);    // [N+1]
    int* cursor_b = rowptr_f + (N + 1);    // [N]
    int* cursor_f = cursor_b + N;          // [N]
    int* eidx_b   = cursor_f + N;          // [E]
    int* eidx_f   = eidx_b + E;            // [E]

    const size_t ws_need = (size_t)((long)8960000 + 520002 + 2) * sizeof(float);
    if (ws_size < ws_need) return;

    // 1) zero deg_b/deg_f (2N ints = 10000 float4)
    zero_kernel<<<dim3((2 * N / 4 + 255) / 256), dim3(256), 0, stream>>>(
        (float4*)deg_b, (long)2 * N / 4);

    const int gN64 = (N + 63) / 64;
    const int gN32 = (N + 31) / 32;
    const int gE64 = (E + 63) / 64;
    const int gE   = (E + 255) / 256;

    // 2-4) CSR build, both directions per dispatch
    hist2_kernel<<<dim3(gE, 2), dim3(256), 0, stream>>>(
        bw_dst, fw_dst, deg_b, deg_f, E);
    scan2_kernel<<<dim3(2), dim3(1024), 0, stream>>>(
        deg_b, deg_f, rowptr_b, rowptr_f, cursor_b, cursor_f, N);
    scatter2_kernel<<<dim3(gE, 2), dim3(256), 0, stream>>>(
        bw_dst, fw_dst, cursor_b, cursor_f, eidx_b, eidx_f, E);

    // 5) five 64->64 node linears in one dispatch
    {
        LinArgs a;
        a.x[0]=u_feat; a.W[0]=w_u;  a.bias[0]=b_u;  a.out[0]=src_he_u; a.ostride[0]=64;
        a.x[1]=v_feat; a.W[1]=w_v;  a.bias[1]=b_v;  a.out[1]=src_he_v; a.ostride[1]=64;
        a.x[2]=v_feat; a.W[2]=w_u;  a.bias[2]=b_u;  a.out[2]=dst_he_v; a.ostride[2]=64;
        a.x[3]=u_feat; a.W[3]=w_Vu; a.bias[3]=b_Vu; a.out[3]=hu;       a.ostride[3]=128;
        a.x[4]=v_feat; a.W[4]=w_Vv; a.bias[4]=b_Vv; a.out[4]=hv;       a.ostride[4]=128;
        lin_batch_kernel<64,64,256,false><<<dim3(gN64, 5), dim3(256), 0, stream>>>(a, N);
    }

    // 6) two 64->128 attention projections in one dispatch
    {
        LinArgs a = {};
        a.x[0]=u_feat; a.W[0]=w_au; a.bias[0]=b_au; a.out[0]=h_att_u; a.ostride[0]=128;
        a.x[1]=v_feat; a.W[1]=w_av; a.bias[1]=b_av; a.out[1]=h_att_v; a.ostride[1]=128;
        lin_batch_kernel<64,128,256,false><<<dim3(gN32, 2), dim3(256), 0, stream>>>(a, N);
    }

    // 7) segmented attention aggregation v3, both directions, no atomics
    agg3_kernel<<<dim3(N, 2), dim3(128), 0, stream>>>(
        v_feat, b_feat, h_att_u, bw_src, eidx_b, rowptr_b, agg_u,
        u_feat, f_feat, h_att_v, fw_src, eidx_f, rowptr_f, agg_v);

    // 8) two 128->64 final linears in one dispatch (right halves of hu/hv)
    {
        LinArgs a = {};
        a.x[0]=agg_u; a.W[0]=w_Wu; a.bias[0]=b_Wu; a.out[0]=hu + 64; a.ostride[0]=128;
        a.x[1]=agg_v; a.W[1]=w_Wv; a.bias[1]=b_Wv; a.out[1]=hv + 64; a.ostride[1]=128;
        lin_batch_kernel<128,64,128,true><<<dim3(gN32, 2), dim3(128), 0, stream>>>(a, N);
    }

    // 9) edge outputs LAST (overwrite h_att scratch in hf):
    //    hf = relu(b_feat@w_e + b_e + src_he_u[bw_src] + src_he_v[bw_dst])
    //    hb = relu(f_feat@w_e + b_e + src_he_u[fw_src] + dst_he_v[fw_dst])
    {
        EdgeArgs a;
        a.x[0]=b_feat; a.tabA[0]=src_he_u; a.tabB[0]=src_he_v;
        a.idxA[0]=bw_src; a.idxB[0]=bw_dst; a.out[0]=hf;
        a.x[1]=f_feat; a.tabA[1]=src_he_u; a.tabB[1]=dst_he_v;
        a.idxA[1]=fw_src; a.idxB[1]=fw_dst; a.out[1]=hb;
        edge_batch_kernel<<<dim3(gE64, 2), dim3(256), 0, stream>>>(a, w_e, b_e, E);
    }
}